// Round 5
// baseline (632.564 us; speedup 1.0000x reference)
//
#include <hip/hip_runtime.h>
#include <stdint.h>

typedef __attribute__((ext_vector_type(8))) short bf16x8;
typedef __attribute__((ext_vector_type(4))) float f32x4;

static constexpr int MNBR   = 12;
static constexpr int AF     = 64;     // atom feature dim
static constexpr int EF     = 41;     // edge feature dim
static constexpr int IN_DIM = 2 * AF + EF;   // 169
static constexpr float BN_EPS = 1e-5f;

// LDS EW tile: 16 rows x 128 ch, row stride 132 u16 (=66 dwords, breaks
// power-of-2 bank strides; all access 2-way conflict max = free)
static constexpr int EW_ROW_U16 = 132;

__device__ __forceinline__ uint16_t f2bfbits(float f) {
    uint32_t x = __float_as_uint(f);
    uint32_t r = x + 0x7fffu + ((x >> 16) & 1u);  // RNE
    return (uint16_t)(r >> 16);
}
__device__ __forceinline__ float softplusf(float x) {
    return fmaxf(x, 0.f) + __logf(1.0f + __expf(-fabsf(x)));
}

// ---------------------------------------------------------------------------
// K0: repack fc_w (fp32) into bf16 MFMA B-fragment order.
// B frag for 16x16x32: lane holds B[k = s*32 + (lane>>4)*8 + j][n = lane&15].
__global__ __launch_bounds__(256) void k_prep(
    const float* __restrict__ fc_w, uint16_t* __restrict__ wp_proj,
    uint16_t* __restrict__ wp_edge)
{
    int e = blockIdx.x * 256 + threadIdx.x;
    if (e < 16384) {
        int j = e & 7, lane = (e >> 3) & 63, s = (e >> 9) & 1, t = e >> 10;
        int n = lane & 15, q = lane >> 4;
        int k = s * 32 + q * 8 + j;
        int c = t * 16 + n;
        float v = (c < 128) ? fc_w[c * IN_DIM + k]
                            : fc_w[(c - 128) * IN_DIM + 64 + k];
        wp_proj[e] = f2bfbits(v);
    } else if (e < 24576) {
        int e2 = e - 16384;
        int j = e2 & 7, lane = (e2 >> 3) & 63, s = (e2 >> 9) & 1, t = e2 >> 10;
        int n = lane & 15, q = lane >> 4;
        int k = s * 32 + q * 8 + j;
        int o = t * 16 + n;
        wp_edge[e2] = (k < EF) ? f2bfbits(fc_w[o * IN_DIM + 2 * AF + k])
                               : (uint16_t)0;
    }
}

// ---------------------------------------------------------------------------
// K1 (MFMA): projection GEMM. Output is PAIR-INTERLEAVED u32:
//   Ps32[n*64+o] = { lo: self ch o (+bias[o]), hi: self ch 64+o (+bias[64+o]) }
//   Pn32[n*64+o] = { lo: nbr  ch o,            hi: nbr  ch 64+o }
// Pair channels (o, o+64) come from wp tiles t and t+4 -> compute both accs
// together and store ONE dword (halves the scattered-store count).
__global__ __launch_bounds__(256) void k_proj(
    const float* __restrict__ atom_in, const uint16_t* __restrict__ wp_proj,
    const float* __restrict__ fc_b, uint32_t* __restrict__ Ps32,
    uint32_t* __restrict__ Pn32, int N)
{
    const int lane = threadIdx.x & 63;
    const int w    = __builtin_amdgcn_readfirstlane((int)(threadIdx.x >> 6));
    const int a0   = blockIdx.x * 64 + w * 16;
    const int mrow = lane & 15, q = lane >> 4;
    const int arow = a0 + mrow;

    bf16x8 A0 = {}, A1 = {};
    if (arow < N) {
        const float* pa = atom_in + (size_t)arow * AF;
#pragma unroll
        for (int j = 0; j < 8; ++j) {
            A0[j] = (short)f2bfbits(pa[q * 8 + j]);       // k = q*8+j
            A1[j] = (short)f2bfbits(pa[32 + q * 8 + j]);  // k = 32+q*8+j
        }
    }

    const bf16x8* wp = (const bf16x8*)wp_proj;
    // self pairs: tiles (t, t+4) -> channels (o, 64+o), o = t*16 + col
#pragma unroll
    for (int t = 0; t < 4; ++t) {
        bf16x8 f0 = wp[((t    ) * 2 + 0) * 64 + lane];
        bf16x8 f1 = wp[((t    ) * 2 + 1) * 64 + lane];
        bf16x8 c0 = wp[((t + 4) * 2 + 0) * 64 + lane];
        bf16x8 c1 = wp[((t + 4) * 2 + 1) * 64 + lane];
        f32x4 af = {0.f, 0.f, 0.f, 0.f}, ac = {0.f, 0.f, 0.f, 0.f};
        af = __builtin_amdgcn_mfma_f32_16x16x32_bf16(A0, f0, af, 0, 0, 0);
        af = __builtin_amdgcn_mfma_f32_16x16x32_bf16(A1, f1, af, 0, 0, 0);
        ac = __builtin_amdgcn_mfma_f32_16x16x32_bf16(A0, c0, ac, 0, 0, 0);
        ac = __builtin_amdgcn_mfma_f32_16x16x32_bf16(A1, c1, ac, 0, 0, 0);
        const int oo = t * 16 + (lane & 15);
        const float bf_ = fc_b[oo], bc_ = fc_b[64 + oo];
#pragma unroll
        for (int r = 0; r < 4; ++r) {
            const int atom = a0 + q * 4 + r;
            if (atom < N) {
                const uint32_t lo = f2bfbits(af[r] + bf_);
                const uint32_t hi = f2bfbits(ac[r] + bc_);
                Ps32[(size_t)atom * 64 + oo] = lo | (hi << 16);
            }
        }
    }
    // nbr pairs: tiles (t+8, t+12) -> channels (128+o, 192+o), bias 0
#pragma unroll
    for (int t = 0; t < 4; ++t) {
        bf16x8 f0 = wp[((t +  8) * 2 + 0) * 64 + lane];
        bf16x8 f1 = wp[((t +  8) * 2 + 1) * 64 + lane];
        bf16x8 c0 = wp[((t + 12) * 2 + 0) * 64 + lane];
        bf16x8 c1 = wp[((t + 12) * 2 + 1) * 64 + lane];
        f32x4 af = {0.f, 0.f, 0.f, 0.f}, ac = {0.f, 0.f, 0.f, 0.f};
        af = __builtin_amdgcn_mfma_f32_16x16x32_bf16(A0, f0, af, 0, 0, 0);
        af = __builtin_amdgcn_mfma_f32_16x16x32_bf16(A1, f1, af, 0, 0, 0);
        ac = __builtin_amdgcn_mfma_f32_16x16x32_bf16(A0, c0, ac, 0, 0, 0);
        ac = __builtin_amdgcn_mfma_f32_16x16x32_bf16(A1, c1, ac, 0, 0, 0);
        const int oo = t * 16 + (lane & 15);
#pragma unroll
        for (int r = 0; r < 4; ++r) {
            const int atom = a0 + q * 4 + r;
            if (atom < N) {
                const uint32_t lo = f2bfbits(af[r]);
                const uint32_t hi = f2bfbits(ac[r]);
                Pn32[(size_t)atom * 64 + oo] = lo | (hi << 16);
            }
        }
    }
}

// ---------------------------------------------------------------------------
// K2/K4: fused conv pass. Block = 384 edge rows = 32 atoms. Wave = 96 rows.
// Round-5: latency-bound -> ILP (occupancy is reg-capped at 2 waves/SIMD).
//  * ONE-TILE-AHEAD prefetch of edge rows + self pairs + 16 gathers, in
//    NAMED double-buffered registers (A/B sets, fully unrolled schedule,
//    zero arrays -> zero scratch risk). Issued at the top of the previous
//    tile's epilogue: edge loads covered by the epilogue VALU work,
//    gathers covered by epilogue + next GEMM.
//  * ew LDS tile double-buffered -> tail barrier per tile removed
//    (6 of 12 barriers gone). R(buf,mt) and W(buf,mt+2) are separated by
//    tile mt+1's barrier.
//  * C->LDS write fused into the GEMM t-loop (acc[8] array gone, -32 VGPR
//    peak pressure).
template <int MODE>
__global__ __launch_bounds__(256) void k_conv(
    const uint32_t* __restrict__ Ps32, const uint32_t* __restrict__ Pn32,
    const float* __restrict__ nbr, const int* __restrict__ idx,
    const uint16_t* __restrict__ wp_edge, const float* __restrict__ bn1coef,
    float* __restrict__ partial, float* __restrict__ nsum, int N)
{
    __shared__ uint16_t ew16[2][4][16 * EW_ROW_U16];   // double-buffered
    __shared__ float red[4][256];
    __shared__ uint16_t bsh[8192];          // staged wp_edge (16 KB)

    const int tid  = threadIdx.x;
    const int lane = tid & 63;
    const int w    = __builtin_amdgcn_readfirstlane((int)(tid >> 6));
    const int col  = lane & 15, q = lane >> 4;
    const int o    = lane;                  // epilogue channel pair (o, o+64)
    (void)N;

    const int rbase = blockIdx.x * 384 + w * 96;   // divisible by 12
    const int nbase = rbase / 12;

    // ---- preload neighbor indices for this wave's 96 rows (2 VGPRs)
    int idxA = idx[rbase + lane];
    int idxB = 0;
    if (lane < 32) idxB = idx[rbase + 64 + lane];

    // ---- stage edge-weight B fragments into LDS (shared by all 4 waves)
    {
        const uint4* s4 = (const uint4*)wp_edge;
        uint4* d4 = (uint4*)bsh;
#pragma unroll
        for (int k = 0; k < 4; ++k) d4[k * 256 + tid] = s4[k * 256 + tid];
    }

    float s1f = 0.f, h1f = 0.f, s1c = 0.f, h1c = 0.f;
    if (MODE == 1) {
        s1f = bn1coef[o];       h1f = bn1coef[128 + o];
        s1c = bn1coef[64 + o];  h1c = bn1coef[192 + o];
    }

    float sA = 0.f, qA = 0.f, sB = 0.f, qB = 0.f;
    float accm = 0.f, psf = 0.f, psc = 0.f;
    const bf16x8* bvs = (const bf16x8*)bsh;

    // ---- named double-buffered prefetch registers (NO arrays)
    f32x4 e0_A, e1_A, e2_A, e3_A; float e4_A;
    f32x4 e0_B, e1_B, e2_B, e3_B; float e4_B;
    uint32_t ps0_A, ps1_A, ps0_B, ps1_B;
    uint32_t pnA0, pnA1, pnA2,  pnA3,  pnA4,  pnA5,  pnA6,  pnA7;
    uint32_t pnA8, pnA9, pnA10, pnA11, pnA12, pnA13, pnA14, pnA15;
    uint32_t pnB0, pnB1, pnB2,  pnB3,  pnB4,  pnB5,  pnB6,  pnB7;
    uint32_t pnB8, pnB9, pnB10, pnB11, pnB12, pnB13, pnB14, pnB15;

#define GATH(mt, S, i)                                                        \
    {                                                                         \
        const int g_ = (mt) * 16 + (i);                                       \
        const int j_ = (g_ < 64) ? __builtin_amdgcn_readlane(idxA, g_)        \
                                 : __builtin_amdgcn_readlane(idxB, g_ - 64);  \
        pn##S##i = Pn32[(size_t)j_ * 64 + o];                                 \
    }

// edge rows FIRST (oldest in vmcnt queue -> A-frag wait leaves newer
// gathers in flight), then self pairs, then the 16 gathers.
#define ISSUE(mt, S)                                                          \
    {                                                                         \
        const float* er_ = nbr + (size_t)(rbase + (mt) * 16 + col) * EF;      \
        __builtin_memcpy(&e0_##S, er_ + q * 8, 16);                           \
        __builtin_memcpy(&e1_##S, er_ + q * 8 + 4, 16);                       \
        e4_##S = 0.f;                                                         \
        if (q == 0) {                                                         \
            __builtin_memcpy(&e2_##S, er_ + 32, 16);                          \
            __builtin_memcpy(&e3_##S, er_ + 36, 16);                          \
        } else if (q == 1) {                                                  \
            e4_##S = er_[40];                                                 \
        }                                                                     \
        const int aA_ = ((mt) * 16 + 11) / 12;                                \
        ps0_##S = 0u; ps1_##S = 0u;                                           \
        if (aA_ * 12 < (mt) * 16 + 16)                                        \
            ps0_##S = Ps32[(size_t)(nbase + aA_) * 64 + o];                   \
        if (aA_ * 12 + 12 < (mt) * 16 + 16)                                   \
            ps1_##S = Ps32[(size_t)(nbase + aA_ + 1) * 64 + o];               \
    }                                                                         \
    GATH(mt, S, 0)  GATH(mt, S, 1)  GATH(mt, S, 2)  GATH(mt, S, 3)            \
    GATH(mt, S, 4)  GATH(mt, S, 5)  GATH(mt, S, 6)  GATH(mt, S, 7)            \
    GATH(mt, S, 8)  GATH(mt, S, 9)  GATH(mt, S, 10) GATH(mt, S, 11)           \
    GATH(mt, S, 12) GATH(mt, S, 13) GATH(mt, S, 14) GATH(mt, S, 15)

// A-frags from prefetched e regs, GEMM, C->LDS fused per t (no acc array).
#define COMPUTE(mt, S)                                                        \
    {                                                                         \
        bf16x8 A0_, A1_ = {};                                                 \
        _Pragma("unroll")                                                     \
        for (int j = 0; j < 4; ++j) {                                         \
            A0_[j]     = (short)f2bfbits(e0_##S[j]);                          \
            A0_[4 + j] = (short)f2bfbits(e1_##S[j]);                          \
        }                                                                     \
        if (q == 0) {                                                         \
            _Pragma("unroll")                                                 \
            for (int j = 0; j < 4; ++j) {                                     \
                A1_[j]     = (short)f2bfbits(e2_##S[j]);                      \
                A1_[4 + j] = (short)f2bfbits(e3_##S[j]);                      \
            }                                                                 \
        } else if (q == 1) {                                                  \
            A1_[0] = (short)f2bfbits(e4_##S);                                 \
        }                                                                     \
        uint16_t* dst_ = &ew16[(mt) & 1][w][0];                               \
        _Pragma("unroll")                                                     \
        for (int t = 0; t < 8; ++t) {                                         \
            bf16x8 b0_ = bvs[(t * 2 + 0) * 64 + lane];                        \
            bf16x8 b1_ = bvs[(t * 2 + 1) * 64 + lane];                        \
            f32x4 a_ = {0.f, 0.f, 0.f, 0.f};                                  \
            a_ = __builtin_amdgcn_mfma_f32_16x16x32_bf16(A0_, b0_, a_, 0, 0, 0); \
            a_ = __builtin_amdgcn_mfma_f32_16x16x32_bf16(A1_, b1_, a_, 0, 0, 0); \
            const int ch_  = t * 16 + col;                                    \
            const int pos_ = (ch_ < 64) ? (ch_ * 2) : ((ch_ - 64) * 2 + 1);   \
            _Pragma("unroll")                                                 \
            for (int r = 0; r < 4; ++r)                                       \
                dst_[(q * 4 + r) * EW_ROW_U16 + pos_] = f2bfbits(a_[r]);      \
        }                                                                     \
    }

#define EPIROW(mt, i, PN)                                                     \
    {                                                                         \
        constexpr int g_ = (mt) * 16 + (i);                                   \
        constexpr int m_ = g_ % 12;                                           \
        if (m_ == 0) {                                                        \
            const uint32_t pp_ = useB_ ? ps1v_ : ps0v_;                       \
            useB_ = true;                                                     \
            psf  = __uint_as_float(pp_ << 16);                                \
            psc  = __uint_as_float(pp_ & 0xffff0000u);                        \
            accm = 0.f;                                                       \
        }                                                                     \
        uint32_t pr_;                                                         \
        __builtin_memcpy(&pr_, &myew_[(i) * EW_ROW_U16 + 2 * o], 4);          \
        const float ewf = __uint_as_float(pr_ << 16);                         \
        const float ewc = __uint_as_float(pr_ & 0xffff0000u);                 \
        const float pnf = __uint_as_float((PN) << 16);                        \
        const float pnc = __uint_as_float((PN) & 0xffff0000u);                \
        const float gf = ewf + psf + pnf;                                     \
        const float gc = ewc + psc + pnc;                                     \
        if (MODE == 0) {                                                      \
            sA += gf; qA = fmaf(gf, gf, qA);                                  \
            sB += gc; qB = fmaf(gc, gc, qB);                                  \
        } else {                                                              \
            const float xf = fmaf(gf, s1f, h1f);                              \
            const float xc = fmaf(gc, s1c, h1c);                              \
            const float filt = 1.0f / (1.0f + __expf(-xf));                   \
            accm = fmaf(filt, softplusf(xc), accm);                           \
            if (m_ == 11) {                                                   \
                nsum[(size_t)(nbase + g_ / 12) * AF + o] = accm;              \
                sB += accm; qB = fmaf(accm, accm, qB);                        \
            }                                                                 \
        }                                                                     \
    }

#define EPILOG(mt, S)                                                         \
    {                                                                         \
        const uint16_t* myew_ = &ew16[(mt) & 1][w][0];                        \
        const uint32_t ps0v_ = ps0_##S, ps1v_ = ps1_##S;                      \
        bool useB_ = false;                                                   \
        EPIROW(mt, 0,  pn##S##0)  EPIROW(mt, 1,  pn##S##1)                    \
        EPIROW(mt, 2,  pn##S##2)  EPIROW(mt, 3,  pn##S##3)                    \
        EPIROW(mt, 4,  pn##S##4)  EPIROW(mt, 5,  pn##S##5)                    \
        EPIROW(mt, 6,  pn##S##6)  EPIROW(mt, 7,  pn##S##7)                    \
        EPIROW(mt, 8,  pn##S##8)  EPIROW(mt, 9,  pn##S##9)                    \
        EPIROW(mt, 10, pn##S##10) EPIROW(mt, 11, pn##S##11)                   \
        EPIROW(mt, 12, pn##S##12) EPIROW(mt, 13, pn##S##13)                   \
        EPIROW(mt, 14, pn##S##14) EPIROW(mt, 15, pn##S##15)                   \
    }

    __syncthreads();   // bsh staged before first GEMM use

    // ---- software-pipelined schedule (fully unrolled, named A/B sets)
    ISSUE(0, A)
    COMPUTE(0, A)
    __syncthreads();
    ISSUE(1, B)  EPILOG(0, A)
    COMPUTE(1, B)
    __syncthreads();
    ISSUE(2, A)  EPILOG(1, B)
    COMPUTE(2, A)
    __syncthreads();
    ISSUE(3, B)  EPILOG(2, A)
    COMPUTE(3, B)
    __syncthreads();
    ISSUE(4, A)  EPILOG(3, B)
    COMPUTE(4, A)
    __syncthreads();
    ISSUE(5, B)  EPILOG(4, A)
    COMPUTE(5, B)
    __syncthreads();
    EPILOG(5, B)

#undef GATH
#undef ISSUE
#undef COMPUTE
#undef EPIROW
#undef EPILOG

    // ---- cross-wave reduction -> per-block partials
    if (MODE == 0) {
        red[w][0 * 64 + lane] = sA;
        red[w][1 * 64 + lane] = qA;
        red[w][2 * 64 + lane] = sB;
        red[w][3 * 64 + lane] = qB;
        __syncthreads();
        const int s = threadIdx.x;            // 0..255
        const int oc = (s & 127) >> 1;
        const int v  = (s >> 7) * 2 + (s & 1);
        const int mp = v * 64 + oc;
        partial[(size_t)blockIdx.x * 256 + s] =
            red[0][mp] + red[1][mp] + red[2][mp] + red[3][mp];
    } else {
        red[w][0 * 64 + lane] = sB;
        red[w][1 * 64 + lane] = qB;
        __syncthreads();
        const int s = threadIdx.x;
        if (s < 128) {
            const int oc = s >> 1;
            const int v  = s & 1;
            const int mp = v * 64 + oc;
            partial[(size_t)blockIdx.x * 128 + s] =
                red[0][mp] + red[1][mp] + red[2][mp] + red[3][mp];
        }
    }
}

// ---------------------------------------------------------------------------
// Reduce per-block partials [NB][2*nch] -> scale/shift per channel.
__global__ __launch_bounds__(256) void k_bn_fin(
    const float* __restrict__ partial, const float* __restrict__ gamma,
    const float* __restrict__ beta, float* __restrict__ coef,
    int nch, int NB, float invR)
{
    const int c = blockIdx.x;
    const int tid = threadIdx.x;
    float s = 0.f, qq = 0.f;
    for (int i = tid; i < NB; i += 256) {
        const float* pp = partial + (size_t)i * (2 * nch) + 2 * c;
        s += pp[0]; qq += pp[1];
    }
    __shared__ float ls[256], lq[256];
    ls[tid] = s; lq[tid] = qq;
    __syncthreads();
    for (int off = 128; off > 0; off >>= 1) {
        if (tid < off) { ls[tid] += ls[tid + off]; lq[tid] += lq[tid + off]; }
        __syncthreads();
    }
    if (tid == 0) {
        float mean = ls[0] * invR;
        float var  = fmaxf(lq[0] * invR - mean * mean, 0.f);
        float sc = gamma[c] * rsqrtf(var + BN_EPS);
        coef[c]       = sc;
        coef[nch + c] = beta[c] - mean * sc;
    }
}

// ---------------------------------------------------------------------------
// K6: out = softplus(atom_in + BN2(nbr_sumed))
__global__ __launch_bounds__(256) void k_final(
    const float* __restrict__ atom_in, const float* __restrict__ nsum,
    const float* __restrict__ bn2, float* __restrict__ out, int total)
{
    int i = blockIdx.x * 256 + threadIdx.x;
    if (i >= total) return;
    int f = i & (AF - 1);
    float v = fmaf(nsum[i], bn2[f], bn2[AF + f]);
    float x = atom_in[i] + v;
    out[i] = softplusf(x);
}

// ---------------------------------------------------------------------------
extern "C" void kernel_launch(void* const* d_in, const int* in_sizes, int n_in,
                              void* d_out, int out_size, void* d_ws, size_t ws_size,
                              hipStream_t stream)
{
    const float* atom_in = (const float*)d_in[0];
    const float* nbr_fea = (const float*)d_in[1];
    const int*   nbr_idx = (const int*)d_in[2];
    const float* fc_w    = (const float*)d_in[3];
    const float* fc_b    = (const float*)d_in[4];
    const float* g1      = (const float*)d_in[5];
    const float* b1      = (const float*)d_in[6];
    const float* g2      = (const float*)d_in[7];
    const float* b2      = (const float*)d_in[8];
    float* out = (float*)d_out;

    const int N = in_sizes[0] / AF;       // 100000 (N % 32 == 0)
    const int conv_blocks = N / 32;       // 3125
    const int NB = conv_blocks;           // per-block partial rows

    // ws budget: ~78.45 MB. p1 aliases nsum (disjoint lifetimes).
    char* ws = (char*)d_ws;
    size_t off = 0;
    uint16_t* wp_proj = (uint16_t*)(ws + off); off += 16384 * 2;
    uint16_t* wp_edge = (uint16_t*)(ws + off); off += 8192 * 2;
    uint16_t* Ps = (uint16_t*)(ws + off); off += (size_t)N * 128 * 2;  // 25.6MB
    uint16_t* Pn = (uint16_t*)(ws + off); off += (size_t)N * 128 * 2;  // 25.6MB
    float* bn1  = (float*)(ws + off);  off += 256 * 4;
    float* bn2c = (float*)(ws + off);  off += 128 * 4;
    off = (off + 511) & ~(size_t)511;
    float* nsum = (float*)(ws + off);
    float* p1   = nsum;                       // alias, 3.2MB < 25.6MB
    off += (size_t)N * AF * 4;
    float* p2   = (float*)(ws + off);  off += (size_t)NB * 128 * 4;

    k_prep<<<96, 256, 0, stream>>>(fc_w, wp_proj, wp_edge);
    k_proj<<<(N + 63) / 64, 256, 0, stream>>>(atom_in, wp_proj, fc_b,
                                              (uint32_t*)Ps, (uint32_t*)Pn, N);
    k_conv<0><<<conv_blocks, 256, 0, stream>>>((const uint32_t*)Ps,
                                               (const uint32_t*)Pn,
                                               nbr_fea, nbr_idx, wp_edge,
                                               nullptr, p1, nullptr, N);
    k_bn_fin<<<128, 256, 0, stream>>>(p1, g1, b1, bn1, 128, NB,
                                      1.0f / (float)(N * MNBR));
    k_conv<1><<<conv_blocks, 256, 0, stream>>>((const uint32_t*)Ps,
                                               (const uint32_t*)Pn,
                                               nbr_fea, nbr_idx, wp_edge,
                                               bn1, p2, nsum, N);
    k_bn_fin<<<64, 256, 0, stream>>>(p2, g2, b2, bn2c, 64, NB, 1.0f / (float)N);

    const int total = N * AF;
    k_final<<<(total + 255) / 256, 256, 0, stream>>>(atom_in, nsum, bn2c, out,
                                                     total);
}

// Round 6
// 598.908 us; speedup vs baseline: 1.0562x; 1.0562x over previous
//
#include <hip/hip_runtime.h>
#include <stdint.h>

typedef __attribute__((ext_vector_type(8))) short bf16x8;
typedef __attribute__((ext_vector_type(4))) float f32x4;

static constexpr int MNBR   = 12;
static constexpr int AF     = 64;     // atom feature dim
static constexpr int EF     = 41;     // edge feature dim
static constexpr int IN_DIM = 2 * AF + EF;   // 169
static constexpr float BN_EPS = 1e-5f;

// LDS EW tile: 16 rows x 128 ch, row stride 132 u16 (=66 dwords, breaks
// power-of-2 bank strides; all access 2-way conflict max = free)
static constexpr int EW_ROW_U16 = 132;

__device__ __forceinline__ uint16_t f2bfbits(float f) {
    uint32_t x = __float_as_uint(f);
    uint32_t r = x + 0x7fffu + ((x >> 16) & 1u);  // RNE
    return (uint16_t)(r >> 16);
}
__device__ __forceinline__ float softplusf(float x) {
    return fmaxf(x, 0.f) + __logf(1.0f + __expf(-fabsf(x)));
}

// Wave-local LDS write->read fence. The ew16 transpose is cross-LANE within
// one wave (each wave owns ew16[w]), so no block barrier is needed — only
// completion of this wave's ds_writes before its ds_reads. sched_barrier
// stops the backend from migrating the reads above the asm (rule: "memory"
// clobber alone does not pin scheduler motion of dependent ops).
__device__ __forceinline__ void wave_lds_fence() {
    asm volatile("s_waitcnt lgkmcnt(0)" ::: "memory");
    __builtin_amdgcn_sched_barrier(0);
}

// ---------------------------------------------------------------------------
// K0: repack fc_w (fp32) into bf16 MFMA B-fragment order.
// B frag for 16x16x32: lane holds B[k = s*32 + (lane>>4)*8 + j][n = lane&15].
__global__ __launch_bounds__(256) void k_prep(
    const float* __restrict__ fc_w, uint16_t* __restrict__ wp_proj,
    uint16_t* __restrict__ wp_edge)
{
    int e = blockIdx.x * 256 + threadIdx.x;
    if (e < 16384) {
        int j = e & 7, lane = (e >> 3) & 63, s = (e >> 9) & 1, t = e >> 10;
        int n = lane & 15, q = lane >> 4;
        int k = s * 32 + q * 8 + j;
        int c = t * 16 + n;
        float v = (c < 128) ? fc_w[c * IN_DIM + k]
                            : fc_w[(c - 128) * IN_DIM + 64 + k];
        wp_proj[e] = f2bfbits(v);
    } else if (e < 24576) {
        int e2 = e - 16384;
        int j = e2 & 7, lane = (e2 >> 3) & 63, s = (e2 >> 9) & 1, t = e2 >> 10;
        int n = lane & 15, q = lane >> 4;
        int k = s * 32 + q * 8 + j;
        int o = t * 16 + n;
        wp_edge[e2] = (k < EF) ? f2bfbits(fc_w[o * IN_DIM + 2 * AF + k])
                               : (uint16_t)0;
    }
}

// ---------------------------------------------------------------------------
// K1 (MFMA): projection GEMM. Output is PAIR-INTERLEAVED u32:
//   Ps32[n*64+o] = { lo: self ch o (+bias[o]), hi: self ch 64+o (+bias[64+o]) }
//   Pn32[n*64+o] = { lo: nbr  ch o,            hi: nbr  ch 64+o }
// Pair channels (o, o+64) come from wp tiles t and t+4 -> compute both accs
// together and store ONE dword (halves the scattered-store count).
__global__ __launch_bounds__(256) void k_proj(
    const float* __restrict__ atom_in, const uint16_t* __restrict__ wp_proj,
    const float* __restrict__ fc_b, uint32_t* __restrict__ Ps32,
    uint32_t* __restrict__ Pn32, int N)
{
    const int lane = threadIdx.x & 63;
    const int w    = __builtin_amdgcn_readfirstlane((int)(threadIdx.x >> 6));
    const int a0   = blockIdx.x * 64 + w * 16;
    const int mrow = lane & 15, q = lane >> 4;
    const int arow = a0 + mrow;

    bf16x8 A0 = {}, A1 = {};
    if (arow < N) {
        const float* pa = atom_in + (size_t)arow * AF;
#pragma unroll
        for (int j = 0; j < 8; ++j) {
            A0[j] = (short)f2bfbits(pa[q * 8 + j]);       // k = q*8+j
            A1[j] = (short)f2bfbits(pa[32 + q * 8 + j]);  // k = 32+q*8+j
        }
    }

    const bf16x8* wp = (const bf16x8*)wp_proj;
    // self pairs: tiles (t, t+4) -> channels (o, 64+o), o = t*16 + col
#pragma unroll
    for (int t = 0; t < 4; ++t) {
        bf16x8 f0 = wp[((t    ) * 2 + 0) * 64 + lane];
        bf16x8 f1 = wp[((t    ) * 2 + 1) * 64 + lane];
        bf16x8 c0 = wp[((t + 4) * 2 + 0) * 64 + lane];
        bf16x8 c1 = wp[((t + 4) * 2 + 1) * 64 + lane];
        f32x4 af = {0.f, 0.f, 0.f, 0.f}, ac = {0.f, 0.f, 0.f, 0.f};
        af = __builtin_amdgcn_mfma_f32_16x16x32_bf16(A0, f0, af, 0, 0, 0);
        af = __builtin_amdgcn_mfma_f32_16x16x32_bf16(A1, f1, af, 0, 0, 0);
        ac = __builtin_amdgcn_mfma_f32_16x16x32_bf16(A0, c0, ac, 0, 0, 0);
        ac = __builtin_amdgcn_mfma_f32_16x16x32_bf16(A1, c1, ac, 0, 0, 0);
        const int oo = t * 16 + (lane & 15);
        const float bf_ = fc_b[oo], bc_ = fc_b[64 + oo];
#pragma unroll
        for (int r = 0; r < 4; ++r) {
            const int atom = a0 + q * 4 + r;
            if (atom < N) {
                const uint32_t lo = f2bfbits(af[r] + bf_);
                const uint32_t hi = f2bfbits(ac[r] + bc_);
                Ps32[(size_t)atom * 64 + oo] = lo | (hi << 16);
            }
        }
    }
    // nbr pairs: tiles (t+8, t+12) -> channels (128+o, 192+o), bias 0
#pragma unroll
    for (int t = 0; t < 4; ++t) {
        bf16x8 f0 = wp[((t +  8) * 2 + 0) * 64 + lane];
        bf16x8 f1 = wp[((t +  8) * 2 + 1) * 64 + lane];
        bf16x8 c0 = wp[((t + 12) * 2 + 0) * 64 + lane];
        bf16x8 c1 = wp[((t + 12) * 2 + 1) * 64 + lane];
        f32x4 af = {0.f, 0.f, 0.f, 0.f}, ac = {0.f, 0.f, 0.f, 0.f};
        af = __builtin_amdgcn_mfma_f32_16x16x32_bf16(A0, f0, af, 0, 0, 0);
        af = __builtin_amdgcn_mfma_f32_16x16x32_bf16(A1, f1, af, 0, 0, 0);
        ac = __builtin_amdgcn_mfma_f32_16x16x32_bf16(A0, c0, ac, 0, 0, 0);
        ac = __builtin_amdgcn_mfma_f32_16x16x32_bf16(A1, c1, ac, 0, 0, 0);
        const int oo = t * 16 + (lane & 15);
#pragma unroll
        for (int r = 0; r < 4; ++r) {
            const int atom = a0 + q * 4 + r;
            if (atom < N) {
                const uint32_t lo = f2bfbits(af[r]);
                const uint32_t hi = f2bfbits(ac[r]);
                Pn32[(size_t)atom * 64 + oo] = lo | (hi << 16);
            }
        }
    }
}

// ---------------------------------------------------------------------------
// K2/K4: fused conv pass. Block = 384 edge rows = 32 atoms. Wave = 96 rows.
// Round-6: the per-tile __syncthreads() were never needed — each wave
// writes/reads ONLY its own ew16[w] slice (the transpose is cross-lane,
// not cross-wave). Replace with wave-local lgkmcnt fences. Waves free-run
// their 6-tile pipelines -> TLP hides gather/edge-load latency. Single-
// buffered ew16 again (LDS 37.4KB -> 4 blocks/CU feasible); single-set
// named prefetch regs to keep VGPR <= 128 for the 4-waves/SIMD tier.
template <int MODE>
__global__ __launch_bounds__(256) void k_conv(
    const uint32_t* __restrict__ Ps32, const uint32_t* __restrict__ Pn32,
    const float* __restrict__ nbr, const int* __restrict__ idx,
    const uint16_t* __restrict__ wp_edge, const float* __restrict__ bn1coef,
    float* __restrict__ partial, float* __restrict__ nsum, int N)
{
    __shared__ uint16_t ew16[4][16 * EW_ROW_U16];
    __shared__ float red[4][256];
    __shared__ uint16_t bsh[8192];          // staged wp_edge (16 KB)

    const int tid  = threadIdx.x;
    const int lane = tid & 63;
    const int w    = __builtin_amdgcn_readfirstlane((int)(tid >> 6));
    const int col  = lane & 15, q = lane >> 4;
    const int o    = lane;                  // epilogue channel pair (o, o+64)
    (void)N;

    const int rbase = blockIdx.x * 384 + w * 96;   // divisible by 12
    const int nbase = rbase / 12;

    // ---- preload neighbor indices for this wave's 96 rows (2 VGPRs)
    int idxA = idx[rbase + lane];
    int idxB = 0;
    if (lane < 32) idxB = idx[rbase + 64 + lane];

    // ---- stage edge-weight B fragments into LDS (shared by all 4 waves)
    {
        const uint4* s4 = (const uint4*)wp_edge;
        uint4* d4 = (uint4*)bsh;
#pragma unroll
        for (int k = 0; k < 4; ++k) d4[k * 256 + tid] = s4[k * 256 + tid];
    }

    float s1f = 0.f, h1f = 0.f, s1c = 0.f, h1c = 0.f;
    if (MODE == 1) {
        s1f = bn1coef[o];       h1f = bn1coef[128 + o];
        s1c = bn1coef[64 + o];  h1c = bn1coef[192 + o];
    }

    float sA = 0.f, qA = 0.f, sB = 0.f, qB = 0.f;
    float accm = 0.f, psf = 0.f, psc = 0.f;
    uint16_t* myew = ew16[w];
    const bf16x8* bvs = (const bf16x8*)bsh;

    // ---- named prefetch registers (NO arrays anywhere)
    f32x4 e0, e1, e2 = {0.f, 0.f, 0.f, 0.f}, e3 = {0.f, 0.f, 0.f, 0.f};
    float e4;
    uint32_t ps0, ps1;
    uint32_t pn0, pn1, pn2,  pn3,  pn4,  pn5,  pn6,  pn7;
    uint32_t pn8, pn9, pn10, pn11, pn12, pn13, pn14, pn15;

#define GATH(mt, i)                                                           \
    {                                                                         \
        const int g_ = (mt) * 16 + (i);                                       \
        const int j_ = (g_ < 64) ? __builtin_amdgcn_readlane(idxA, g_)        \
                                 : __builtin_amdgcn_readlane(idxB, g_ - 64);  \
        pn##i = Pn32[(size_t)j_ * 64 + o];                                    \
    }

// edge rows FIRST (oldest in vmcnt queue -> A-frag wait is a counted vmcnt
// leaving the newer gathers in flight under the GEMM), then self pairs,
// then the 16 gathers.
#define ISSUE(mt)                                                             \
    {                                                                         \
        const float* er_ = nbr + (size_t)(rbase + (mt) * 16 + col) * EF;      \
        __builtin_memcpy(&e0, er_ + q * 8, 16);                               \
        __builtin_memcpy(&e1, er_ + q * 8 + 4, 16);                           \
        e4 = 0.f;                                                             \
        if (q == 0) {                                                         \
            __builtin_memcpy(&e2, er_ + 32, 16);                              \
            __builtin_memcpy(&e3, er_ + 36, 16);                              \
        } else if (q == 1) {                                                  \
            e4 = er_[40];                                                     \
        }                                                                     \
        const int aA_ = ((mt) * 16 + 11) / 12;                                \
        ps0 = 0u; ps1 = 0u;                                                   \
        if (aA_ * 12 < (mt) * 16 + 16)                                        \
            ps0 = Ps32[(size_t)(nbase + aA_) * 64 + o];                       \
        if (aA_ * 12 + 12 < (mt) * 16 + 16)                                   \
            ps1 = Ps32[(size_t)(nbase + aA_ + 1) * 64 + o];                   \
    }                                                                         \
    GATH(mt, 0)  GATH(mt, 1)  GATH(mt, 2)  GATH(mt, 3)                        \
    GATH(mt, 4)  GATH(mt, 5)  GATH(mt, 6)  GATH(mt, 7)                        \
    GATH(mt, 8)  GATH(mt, 9)  GATH(mt, 10) GATH(mt, 11)                       \
    GATH(mt, 12) GATH(mt, 13) GATH(mt, 14) GATH(mt, 15)

// A-frags from e regs, GEMM from LDS-staged B, C->LDS write fused per t.
#define COMPUTE(mt)                                                           \
    {                                                                         \
        bf16x8 A0_, A1_ = {};                                                 \
        _Pragma("unroll")                                                     \
        for (int j = 0; j < 4; ++j) {                                         \
            A0_[j]     = (short)f2bfbits(e0[j]);                              \
            A0_[4 + j] = (short)f2bfbits(e1[j]);                              \
        }                                                                     \
        if (q == 0) {                                                         \
            _Pragma("unroll")                                                 \
            for (int j = 0; j < 4; ++j) {                                     \
                A1_[j]     = (short)f2bfbits(e2[j]);                          \
                A1_[4 + j] = (short)f2bfbits(e3[j]);                          \
            }                                                                 \
        } else if (q == 1) {                                                  \
            A1_[0] = (short)f2bfbits(e4);                                     \
        }                                                                     \
        _Pragma("unroll")                                                     \
        for (int t = 0; t < 8; ++t) {                                         \
            bf16x8 b0_ = bvs[(t * 2 + 0) * 64 + lane];                        \
            bf16x8 b1_ = bvs[(t * 2 + 1) * 64 + lane];                        \
            f32x4 a_ = {0.f, 0.f, 0.f, 0.f};                                  \
            a_ = __builtin_amdgcn_mfma_f32_16x16x32_bf16(A0_, b0_, a_, 0, 0, 0); \
            a_ = __builtin_amdgcn_mfma_f32_16x16x32_bf16(A1_, b1_, a_, 0, 0, 0); \
            const int ch_  = t * 16 + col;                                    \
            const int pos_ = (ch_ < 64) ? (ch_ * 2) : ((ch_ - 64) * 2 + 1);   \
            _Pragma("unroll")                                                 \
            for (int r = 0; r < 4; ++r)                                       \
                myew[(q * 4 + r) * EW_ROW_U16 + pos_] = f2bfbits(a_[r]);      \
        }                                                                     \
    }

#define EPIROW(mt, i, PN)                                                     \
    {                                                                         \
        constexpr int g_ = (mt) * 16 + (i);                                   \
        constexpr int m_ = g_ % 12;                                           \
        if (m_ == 0) {                                                        \
            const uint32_t pp_ = useB_ ? ps1 : ps0;                           \
            useB_ = true;                                                     \
            psf  = __uint_as_float(pp_ << 16);                                \
            psc  = __uint_as_float(pp_ & 0xffff0000u);                        \
            accm = 0.f;                                                       \
        }                                                                     \
        uint32_t pr_;                                                         \
        __builtin_memcpy(&pr_, &myew[(i) * EW_ROW_U16 + 2 * o], 4);           \
        const float ewf = __uint_as_float(pr_ << 16);                         \
        const float ewc = __uint_as_float(pr_ & 0xffff0000u);                 \
        const float pnf = __uint_as_float((PN) << 16);                        \
        const float pnc = __uint_as_float((PN) & 0xffff0000u);                \
        const float gf = ewf + psf + pnf;                                     \
        const float gc = ewc + psc + pnc;                                     \
        if (MODE == 0) {                                                      \
            sA += gf; qA = fmaf(gf, gf, qA);                                  \
            sB += gc; qB = fmaf(gc, gc, qB);                                  \
        } else {                                                              \
            const float xf = fmaf(gf, s1f, h1f);                              \
            const float xc = fmaf(gc, s1c, h1c);                              \
            const float filt = 1.0f / (1.0f + __expf(-xf));                   \
            accm = fmaf(filt, softplusf(xc), accm);                           \
            if (m_ == 11) {                                                   \
                nsum[(size_t)(nbase + g_ / 12) * AF + o] = accm;              \
                sB += accm; qB = fmaf(accm, accm, qB);                        \
            }                                                                 \
        }                                                                     \
    }

#define EPILOG(mt)                                                            \
    {                                                                         \
        bool useB_ = false;                                                   \
        EPIROW(mt, 0,  pn0)  EPIROW(mt, 1,  pn1)                              \
        EPIROW(mt, 2,  pn2)  EPIROW(mt, 3,  pn3)                              \
        EPIROW(mt, 4,  pn4)  EPIROW(mt, 5,  pn5)                              \
        EPIROW(mt, 6,  pn6)  EPIROW(mt, 7,  pn7)                              \
        EPIROW(mt, 8,  pn8)  EPIROW(mt, 9,  pn9)                              \
        EPIROW(mt, 10, pn10) EPIROW(mt, 11, pn11)                             \
        EPIROW(mt, 12, pn12) EPIROW(mt, 13, pn13)                             \
        EPIROW(mt, 14, pn14) EPIROW(mt, 15, pn15)                             \
    }

// Per tile: no block barrier anywhere. wave_lds_fence orders this wave's
// ds_writes before its own ds_reads; the tile-end sched_barrier keeps the
// next tile's ds_writes behind these ds_reads (same buffer).
#define TILE(mt)                                                              \
    ISSUE(mt)                                                                 \
    COMPUTE(mt)                                                               \
    wave_lds_fence();                                                         \
    EPILOG(mt)                                                                \
    __builtin_amdgcn_sched_barrier(0);

    __syncthreads();   // bsh staged before first GEMM use

    TILE(0) TILE(1) TILE(2) TILE(3) TILE(4) TILE(5)

#undef GATH
#undef ISSUE
#undef COMPUTE
#undef EPIROW
#undef EPILOG
#undef TILE

    // ---- cross-wave reduction -> per-block partials
    if (MODE == 0) {
        red[w][0 * 64 + lane] = sA;
        red[w][1 * 64 + lane] = qA;
        red[w][2 * 64 + lane] = sB;
        red[w][3 * 64 + lane] = qB;
        __syncthreads();
        const int s = threadIdx.x;            // 0..255
        const int oc = (s & 127) >> 1;
        const int v  = (s >> 7) * 2 + (s & 1);
        const int mp = v * 64 + oc;
        partial[(size_t)blockIdx.x * 256 + s] =
            red[0][mp] + red[1][mp] + red[2][mp] + red[3][mp];
    } else {
        red[w][0 * 64 + lane] = sB;
        red[w][1 * 64 + lane] = qB;
        __syncthreads();
        const int s = threadIdx.x;
        if (s < 128) {
            const int oc = s >> 1;
            const int v  = s & 1;
            const int mp = v * 64 + oc;
            partial[(size_t)blockIdx.x * 128 + s] =
                red[0][mp] + red[1][mp] + red[2][mp] + red[3][mp];
        }
    }
}

// ---------------------------------------------------------------------------
// Reduce per-block partials [NB][2*nch] -> scale/shift per channel.
__global__ __launch_bounds__(256) void k_bn_fin(
    const float* __restrict__ partial, const float* __restrict__ gamma,
    const float* __restrict__ beta, float* __restrict__ coef,
    int nch, int NB, float invR)
{
    const int c = blockIdx.x;
    const int tid = threadIdx.x;
    float s = 0.f, qq = 0.f;
    for (int i = tid; i < NB; i += 256) {
        const float* pp = partial + (size_t)i * (2 * nch) + 2 * c;
        s += pp[0]; qq += pp[1];
    }
    __shared__ float ls[256], lq[256];
    ls[tid] = s; lq[tid] = qq;
    __syncthreads();
    for (int off = 128; off > 0; off >>= 1) {
        if (tid < off) { ls[tid] += ls[tid + off]; lq[tid] += lq[tid + off]; }
        __syncthreads();
    }
    if (tid == 0) {
        float mean = ls[0] * invR;
        float var  = fmaxf(lq[0] * invR - mean * mean, 0.f);
        float sc = gamma[c] * rsqrtf(var + BN_EPS);
        coef[c]       = sc;
        coef[nch + c] = beta[c] - mean * sc;
    }
}

// ---------------------------------------------------------------------------
// K6: out = softplus(atom_in + BN2(nbr_sumed))
__global__ __launch_bounds__(256) void k_final(
    const float* __restrict__ atom_in, const float* __restrict__ nsum,
    const float* __restrict__ bn2, float* __restrict__ out, int total)
{
    int i = blockIdx.x * 256 + threadIdx.x;
    if (i >= total) return;
    int f = i & (AF - 1);
    float v = fmaf(nsum[i], bn2[f], bn2[AF + f]);
    float x = atom_in[i] + v;
    out[i] = softplusf(x);
}

// ---------------------------------------------------------------------------
extern "C" void kernel_launch(void* const* d_in, const int* in_sizes, int n_in,
                              void* d_out, int out_size, void* d_ws, size_t ws_size,
                              hipStream_t stream)
{
    const float* atom_in = (const float*)d_in[0];
    const float* nbr_fea = (const float*)d_in[1];
    const int*   nbr_idx = (const int*)d_in[2];
    const float* fc_w    = (const float*)d_in[3];
    const float* fc_b    = (const float*)d_in[4];
    const float* g1      = (const float*)d_in[5];
    const float* b1      = (const float*)d_in[6];
    const float* g2      = (const float*)d_in[7];
    const float* b2      = (const float*)d_in[8];
    float* out = (float*)d_out;

    const int N = in_sizes[0] / AF;       // 100000 (N % 32 == 0)
    const int conv_blocks = N / 32;       // 3125
    const int NB = conv_blocks;           // per-block partial rows

    // ws budget: ~78.45 MB. p1 aliases nsum (disjoint lifetimes).
    char* ws = (char*)d_ws;
    size_t off = 0;
    uint16_t* wp_proj = (uint16_t*)(ws + off); off += 16384 * 2;
    uint16_t* wp_edge = (uint16_t*)(ws + off); off += 8192 * 2;
    uint16_t* Ps = (uint16_t*)(ws + off); off += (size_t)N * 128 * 2;  // 25.6MB
    uint16_t* Pn = (uint16_t*)(ws + off); off += (size_t)N * 128 * 2;  // 25.6MB
    float* bn1  = (float*)(ws + off);  off += 256 * 4;
    float* bn2c = (float*)(ws + off);  off += 128 * 4;
    off = (off + 511) & ~(size_t)511;
    float* nsum = (float*)(ws + off);
    float* p1   = nsum;                       // alias, 3.2MB < 25.6MB
    off += (size_t)N * AF * 4;
    float* p2   = (float*)(ws + off);  off += (size_t)NB * 128 * 4;

    k_prep<<<96, 256, 0, stream>>>(fc_w, wp_proj, wp_edge);
    k_proj<<<(N + 63) / 64, 256, 0, stream>>>(atom_in, wp_proj, fc_b,
                                              (uint32_t*)Ps, (uint32_t*)Pn, N);
    k_conv<0><<<conv_blocks, 256, 0, stream>>>((const uint32_t*)Ps,
                                               (const uint32_t*)Pn,
                                               nbr_fea, nbr_idx, wp_edge,
                                               nullptr, p1, nullptr, N);
    k_bn_fin<<<128, 256, 0, stream>>>(p1, g1, b1, bn1, 128, NB,
                                      1.0f / (float)(N * MNBR));
    k_conv<1><<<conv_blocks, 256, 0, stream>>>((const uint32_t*)Ps,
                                               (const uint32_t*)Pn,
                                               nbr_fea, nbr_idx, wp_edge,
                                               bn1, p2, nsum, N);
    k_bn_fin<<<64, 256, 0, stream>>>(p2, g2, b2, bn2c, 64, NB, 1.0f / (float)N);

    const int total = N * AF;
    k_final<<<(total + 255) / 256, 256, 0, stream>>>(atom_in, nsum, bn2c, out,
                                                     total);
}